// Round 17
// baseline (205.979 us; speedup 1.0000x reference)
//
#include <hip/hip_runtime.h>
#include <hip/hip_bf16.h>

#define Hh 50

typedef __attribute__((ext_vector_type(8))) short bf16x8;
typedef __attribute__((ext_vector_type(4))) float f32x4;

static __device__ __forceinline__ short b16(float x) {
    return __builtin_bit_cast(short, __float2bfloat16(x));
}
// convert 8 contiguous f32 to a bf16x8 MFMA fragment
static __device__ __forceinline__ bf16x8 cvt8(const float* p) {
    f32x4 a = *(const f32x4*)p;
    f32x4 b = *(const f32x4*)(p + 4);
    bf16x8 r;
    r[0] = b16(a[0]); r[1] = b16(a[1]); r[2] = b16(a[2]); r[3] = b16(a[3]);
    r[4] = b16(b[0]); r[5] = b16(b[1]); r[6] = b16(b[2]); r[7] = b16(b[3]);
    return r;
}

// -------- Kernel 0: pack wh_w into 16x16x32 B-fragment order, replicated 8x --------
// whpk[c*65536 + ((p*8+ks)*64+l)*8+j] = bf16(wh_w[p*16+(l&15)][ks*32+(l>>4)*8+j])
__global__ __launch_bounds__(256) void k_prep(const float* __restrict__ w,
                                              short* __restrict__ o) {
    int t = (int)blockIdx.x * 256 + threadIdx.x;   // 0..8191
    int p  = t >> 9;
    int ks = (t >> 6) & 7;
    int l  = t & 63;
    int col = p * 16 + (l & 15);
    int k   = ks * 32 + (l >> 4) * 8;
    bf16x8 v = cvt8(w + (size_t)col * 256 + k);
#pragma unroll
    for (int c = 0; c < 8; c++)
        *(bf16x8*)(o + (size_t)c * 65536 + (size_t)t * 8) = v;
}

// ---------------- Kernel 1: wc_out[4096][256] (f32) = cur @ wc_w^T + wc_b ----------------
__global__ __launch_bounds__(64) void k_wc(const float* __restrict__ cur,
                                           const float* __restrict__ wcw,
                                           const float* __restrict__ wcb,
                                           float* __restrict__ out) {
    int l = threadIdx.x;
    int m0 = (int)(blockIdx.x >> 2) * 16;
    int ntb = (int)(blockIdx.x & 3) * 4;
    int lk = (l >> 4) * 8;

    bf16x8 Af[8];
#pragma unroll
    for (int k = 0; k < 8; k++)
        Af[k] = cvt8(cur + (size_t)(m0 + (l & 15)) * 256 + k * 32 + lk);

#pragma unroll
    for (int nt = 0; nt < 4; nt++) {
        int col = (ntb + nt) * 16 + (l & 15);
        f32x4 a = {0.f, 0.f, 0.f, 0.f};
#pragma unroll
        for (int k = 0; k < 8; k++) {
            bf16x8 Bf = cvt8(wcw + (size_t)col * 256 + k * 32 + lk);
            a = __builtin_amdgcn_mfma_f32_16x16x32_bf16(Af[k], Bf, a, 0, 0, 0);
        }
        float bias = wcb[col];
        int row = m0 + (l >> 4) * 4;
#pragma unroll
        for (int r = 0; r < 4; r++)
            out[(size_t)(row + r) * 256 + col] = a[r] + bias;
    }
}

// ---------------- Kernel 2: persistent-B fused wh GEMM + sigmoid + qt + alpha*hist -------
// 512 blocks x 512 thr (8 waves). Wave w holds B panel (cols 32w..32w+31, all K=256):
// 16 frags = 64 VGPR, loaded ONCE. Block loops over 8 items (b=i, s=blockIdx) --
// consecutive blocks stage ADJACENT 1KB hist rows (page-local). Per item:
// stage -> 64 MFMAs/wave (8 indep chains, acc[4m][2nt] AGPR) -> sigmoid epilogue ->
// 8-wave reduce -> fused hsum. No global loads inside the GEMM.
__global__ __launch_bounds__(512, 4)
void k_main(const float* __restrict__ hist,
            const float* __restrict__ wc_ws,
            const short* __restrict__ whpk,
            const float* __restrict__ whb,
            const float* __restrict__ qtw,
            const float* __restrict__ qtb,
            float* __restrict__ hsum_ws) {
    __shared__ __align__(16) char histA[64 * 512];   // swizzled bf16 [row][256]
    __shared__ float wcrow[256];                     // wc_out[b,s,:] + wh_b
    __shared__ float qtl[256];
    __shared__ float alphaP[8][64];
    __shared__ float alphaF[64];
    __shared__ float hp[2][256];

    int tid = threadIdx.x;
    int l = tid & 63;
    int w = tid >> 6;                 // 0..7
    int s = (int)blockIdx.x;          // 0..511
    const short* whq = whpk + (size_t)(blockIdx.x & 7) * 65536;

    // ---- persistent B: this wave's 32-col panel, all K (16 frags = 64 VGPR) ----
    bf16x8 Bp[2][8];
#pragma unroll
    for (int nt2 = 0; nt2 < 2; nt2++)
#pragma unroll
        for (int ks = 0; ks < 8; ks++) {
            int p = w * 2 + nt2;
            Bp[nt2][ks] = *(const bf16x8*)(whq + ((size_t)((p * 8 + ks) * 64 + l)) * 8);
        }

#pragma unroll 1
    for (int b = 0; b < 8; b++) {
        __syncthreads();   // protect histA/wcrow vs previous item's readers

        // stage 50 hist rows (f32 -> bf16) into swizzled LDS
        for (int c = tid; c < 1600; c += 512) {
            int r = c >> 5, g = c & 31;
            bf16x8 v = cvt8(hist + ((size_t)(b * Hh + r) * 512 + s) * 256 + g * 8);
            *(bf16x8*)(&histA[r * 512 + ((g ^ (r & 15)) << 4)]) = v;
        }
        if (tid < 448) {   // zero pad rows 50..63
            int r = 50 + (tid >> 5), g = tid & 31;
            *(f32x4*)(&histA[r * 512 + ((g ^ (r & 15)) << 4)]) = (f32x4){0.f, 0.f, 0.f, 0.f};
        }
        if (tid < 256) {
            wcrow[tid] = wc_ws[(size_t)(b * 512 + s) * 256 + tid] + whb[tid];
            qtl[tid] = qtw[tid];
        }
        __syncthreads();

        // ---- GEMM: 4m x 2nt x 8ks, pure LDS-A + register-B ----
        f32x4 acc[4][2];
#pragma unroll
        for (int m = 0; m < 4; m++)
#pragma unroll
            for (int nt2 = 0; nt2 < 2; nt2++)
                acc[m][nt2] = (f32x4){0.f, 0.f, 0.f, 0.f};

#pragma unroll
        for (int ks = 0; ks < 8; ks++) {
#pragma unroll
            for (int m = 0; m < 4; m++) {
                int rA = m * 16 + (l & 15);
                int g = ks * 4 + (l >> 4);
                bf16x8 Am = *(const bf16x8*)(&histA[rA * 512 + ((g ^ (rA & 15)) << 4)]);
#pragma unroll
                for (int nt2 = 0; nt2 < 2; nt2++)
                    acc[m][nt2] = __builtin_amdgcn_mfma_f32_16x16x32_bf16(
                        Am, Bp[nt2][ks], acc[m][nt2], 0, 0, 0);
            }
        }

        // ---- epilogue: sigmoid + qt over this wave's 32 cols ----
        float pal[4][4];
#pragma unroll
        for (int m = 0; m < 4; m++)
#pragma unroll
            for (int r = 0; r < 4; r++) pal[m][r] = 0.f;

#pragma unroll
        for (int m = 0; m < 4; m++)
#pragma unroll
            for (int nt2 = 0; nt2 < 2; nt2++) {
                int col = w * 32 + nt2 * 16 + (l & 15);
                float qv = qtl[col], wb = wcrow[col];
#pragma unroll
                for (int r = 0; r < 4; r++) {
                    float v = acc[m][nt2][r] + wb;
                    pal[m][r] += qv * __builtin_amdgcn_rcpf(1.0f + __expf(-v));
                }
            }

#pragma unroll
        for (int m = 0; m < 4; m++)
#pragma unroll
            for (int r = 0; r < 4; r++) {
                float v = pal[m][r];
                v += __shfl_xor(v, 1);
                v += __shfl_xor(v, 2);
                v += __shfl_xor(v, 4);
                v += __shfl_xor(v, 8);
                if ((l & 15) == 0)
                    alphaP[w][m * 16 + (l >> 4) * 4 + r] = v;
            }
        __syncthreads();
        if (tid < Hh)
            alphaF[tid] = qtb[0] + alphaP[0][tid] + alphaP[1][tid] + alphaP[2][tid] + alphaP[3][tid]
                        + alphaP[4][tid] + alphaP[5][tid] + alphaP[6][tid] + alphaP[7][tid];
        __syncthreads();

        // ---- history_sum: 2-way h-split, one col per (half,thread) ----
        {
            int d = tid & 255;
            int half = tid >> 8;
            float a = 0.f;
#pragma unroll
            for (int hh = 0; hh < 25; hh++) {
                int h = half * 25 + hh;
                int g = (d >> 3) ^ (h & 15);
                unsigned short u = *(const unsigned short*)(&histA[h * 512 + (g << 4) + (d & 7) * 2]);
                unsigned int x = ((unsigned int)u) << 16;
                a += alphaF[h] * __builtin_bit_cast(float, x);
            }
            hp[half][d] = a;
        }
        __syncthreads();
        if (tid < 256)
            hsum_ws[(size_t)(b * 512 + s) * 256 + tid] = hp[0][tid] + hp[1][tid];
    }
}

// ---------------- Kernel 3: out[4096][128] (f32) = [cur, hsum] @ wf_w^T + wf_b ----------------
__global__ __launch_bounds__(64) void k_wf(const float* __restrict__ cur,
                                           const float* __restrict__ hsum,
                                           const float* __restrict__ wfw,
                                           const float* __restrict__ wfb,
                                           float* __restrict__ out) {
    int l = threadIdx.x;
    int m0 = (int)(blockIdx.x >> 1) * 16;
    int ntb = (int)(blockIdx.x & 1) * 4;
    int lk = (l >> 4) * 8;

    f32x4 acc[4];
#pragma unroll
    for (int nt = 0; nt < 4; nt++) acc[nt] = (f32x4){0.f, 0.f, 0.f, 0.f};

#pragma unroll
    for (int k = 0; k < 16; k++) {
        int row = m0 + (l & 15);
        bf16x8 Af;
        if (k < 8)
            Af = cvt8(cur + (size_t)row * 256 + k * 32 + lk);
        else
            Af = cvt8(hsum + (size_t)row * 256 + (k - 8) * 32 + lk);
#pragma unroll
        for (int nt = 0; nt < 4; nt++) {
            int col = (ntb + nt) * 16 + (l & 15);
            bf16x8 Bf = cvt8(wfw + (size_t)col * 512 + k * 32 + lk);
            acc[nt] = __builtin_amdgcn_mfma_f32_16x16x32_bf16(Af, Bf, acc[nt], 0, 0, 0);
        }
    }
#pragma unroll
    for (int nt = 0; nt < 4; nt++) {
        int col = (ntb + nt) * 16 + (l & 15);
        float bias = wfb[col];
        int row = m0 + (l >> 4) * 4;
#pragma unroll
        for (int r = 0; r < 4; r++)
            out[(size_t)(row + r) * 128 + col] = acc[nt][r] + bias;
    }
}

extern "C" void kernel_launch(void* const* d_in, const int* in_sizes, int n_in,
                              void* d_out, int out_size, void* d_ws, size_t ws_size,
                              hipStream_t stream) {
    const float* hist = (const float*)d_in[0];
    const float* cur  = (const float*)d_in[1];
    const float* wc_w = (const float*)d_in[2];
    const float* wc_b = (const float*)d_in[3];
    const float* wh_w = (const float*)d_in[4];
    const float* wh_b = (const float*)d_in[5];
    const float* qt_w = (const float*)d_in[6];
    const float* qt_b = (const float*)d_in[7];
    const float* wf_w = (const float*)d_in[8];
    const float* wf_b = (const float*)d_in[9];

    float* wc_ws = (float*)d_ws;                                   // 4 MB
    float* hsum  = (float*)((char*)d_ws + ((size_t)4 << 20));      // 4 MB
    short* whpk  = (short*)((char*)d_ws + ((size_t)8 << 20));      // 8 x 128 KB replicas

    k_prep<<<32, 256, 0, stream>>>(wh_w, whpk);
    k_wc<<<1024, 64, 0, stream>>>(cur, wc_w, wc_b, wc_ws);
    k_main<<<512, 512, 0, stream>>>(hist, wc_ws, whpk, wh_b, qt_w, qt_b, hsum);
    k_wf<<<512, 64, 0, stream>>>(cur, hsum, wf_w, wf_b, (float*)d_out);
}

// Round 18
// 146.511 us; speedup vs baseline: 1.4059x; 1.4059x over previous
//
#include <hip/hip_runtime.h>
#include <hip/hip_bf16.h>

#define Hh 50

typedef __attribute__((ext_vector_type(8))) short bf16x8;
typedef __attribute__((ext_vector_type(4))) float f32x4;

static __device__ __forceinline__ short b16(float x) {
    return __builtin_bit_cast(short, __float2bfloat16(x));
}
// convert 8 contiguous f32 to a bf16x8 MFMA fragment
static __device__ __forceinline__ bf16x8 cvt8(const float* p) {
    f32x4 a = *(const f32x4*)p;
    f32x4 b = *(const f32x4*)(p + 4);
    bf16x8 r;
    r[0] = b16(a[0]); r[1] = b16(a[1]); r[2] = b16(a[2]); r[3] = b16(a[3]);
    r[4] = b16(b[0]); r[5] = b16(b[1]); r[6] = b16(b[2]); r[7] = b16(b[3]);
    return r;
}
// same, but NON-TEMPORAL (nt flag): evict-first, minimal L2 pollution.
// Used for the big read-once streams (hist, wc_ws) so whpk stays L2-resident.
static __device__ __forceinline__ bf16x8 cvt8_nt(const float* p) {
    f32x4 a = __builtin_nontemporal_load((const f32x4*)p);
    f32x4 b = __builtin_nontemporal_load((const f32x4*)(p + 4));
    bf16x8 r;
    r[0] = b16(a[0]); r[1] = b16(a[1]); r[2] = b16(a[2]); r[3] = b16(a[3]);
    r[4] = b16(b[0]); r[5] = b16(b[1]); r[6] = b16(b[2]); r[7] = b16(b[3]);
    return r;
}

// -------- Kernel 0: pack wh_w into 16x16x32 B-fragment order, replicated 8x --------
// whpk[c*65536 + ((p*8+ks)*64+l)*8+j] = bf16(wh_w[p*16+(l&15)][ks*32+(l>>4)*8+j])
__global__ __launch_bounds__(256) void k_prep(const float* __restrict__ w,
                                              short* __restrict__ o) {
    int t = (int)blockIdx.x * 256 + threadIdx.x;   // 0..8191
    int p  = t >> 9;
    int ks = (t >> 6) & 7;
    int l  = t & 63;
    int col = p * 16 + (l & 15);
    int k   = ks * 32 + (l >> 4) * 8;
    bf16x8 v = cvt8(w + (size_t)col * 256 + k);
#pragma unroll
    for (int c = 0; c < 8; c++)
        *(bf16x8*)(o + (size_t)c * 65536 + (size_t)t * 8) = v;
}

// ---------------- Kernel 1: wc_out[4096][256] (f32) = cur @ wc_w^T + wc_b ----------------
__global__ __launch_bounds__(64) void k_wc(const float* __restrict__ cur,
                                           const float* __restrict__ wcw,
                                           const float* __restrict__ wcb,
                                           float* __restrict__ out) {
    int l = threadIdx.x;
    int m0 = (int)(blockIdx.x >> 2) * 16;
    int ntb = (int)(blockIdx.x & 3) * 4;
    int lk = (l >> 4) * 8;

    bf16x8 Af[8];
#pragma unroll
    for (int k = 0; k < 8; k++)
        Af[k] = cvt8(cur + (size_t)(m0 + (l & 15)) * 256 + k * 32 + lk);

#pragma unroll
    for (int nt = 0; nt < 4; nt++) {
        int col = (ntb + nt) * 16 + (l & 15);
        f32x4 a = {0.f, 0.f, 0.f, 0.f};
#pragma unroll
        for (int k = 0; k < 8; k++) {
            bf16x8 Bf = cvt8(wcw + (size_t)col * 256 + k * 32 + lk);
            a = __builtin_amdgcn_mfma_f32_16x16x32_bf16(Af[k], Bf, a, 0, 0, 0);
        }
        float bias = wcb[col];
        int row = m0 + (l >> 4) * 4;
#pragma unroll
        for (int r = 0; r < 4; r++)
            out[(size_t)(row + r) * 256 + col] = a[r] + bias;
    }
}

// ---------------- Kernel 2: fused wh GEMM + sigmoid + qt dot + alpha*hist ----------------
// Identical to round 15 except the hist/wc_ws streams use NON-TEMPORAL loads so they
// cannot evict whpk from L2 (theory: B reads were L3-served at ~6 TB/s due to thrash).
__global__ __launch_bounds__(256, 3)
void k_main(const float* __restrict__ hist,
            const float* __restrict__ wc_ws,
            const short* __restrict__ whpk,
            const float* __restrict__ whb,
            const float* __restrict__ qtw,
            const float* __restrict__ qtb,
            float* __restrict__ hsum_ws) {
    __shared__ __align__(16) char histA[64 * 512];   // swizzled bf16 [row][256]
    __shared__ float wcrow[256];                     // wc_out[b,s,:] + wh_b
    __shared__ float qtl[256];
    __shared__ float alphaP[4][64];
    __shared__ float alphaF[64];

    int tid = threadIdx.x;
    int l = tid & 63;
    int w = tid >> 6;
    int b = (int)(blockIdx.x >> 9);
    int s = (int)(blockIdx.x & 511);
    const short* whq = whpk + (size_t)(blockIdx.x & 7) * 65536;

    // stage 50 hist rows (f32 -> bf16) into swizzled LDS — non-temporal
    for (int c = tid; c < 1600; c += 256) {
        int r = c >> 5, g = c & 31;
        bf16x8 v = cvt8_nt(hist + ((size_t)(b * Hh + r) * 512 + s) * 256 + g * 8);
        *(bf16x8*)(&histA[r * 512 + ((g ^ (r & 15)) << 4)]) = v;
    }
    // zero pad rows 50..63
    if (tid < 448) {
        int r = 50 + (tid >> 5), g = tid & 31;
        *(f32x4*)(&histA[r * 512 + ((g ^ (r & 15)) << 4)]) = (f32x4){0.f, 0.f, 0.f, 0.f};
    }
    wcrow[tid] = __builtin_nontemporal_load(wc_ws + (size_t)(b * 512 + s) * 256 + tid) + whb[tid];
    qtl[tid] = qtw[tid];
    __syncthreads();

    f32x4 acc[4][4];
#pragma unroll
    for (int m = 0; m < 4; m++)
#pragma unroll
        for (int nt = 0; nt < 4; nt++)
            acc[m][nt] = (f32x4){0.f, 0.f, 0.f, 0.f};

#pragma unroll 1
    for (int half = 0; half < 2; half++) {
        // one burst: this wave's B half-panel, 16 contiguous-per-frag loads (cached)
        bf16x8 Bh[4][4];
#pragma unroll
        for (int nt = 0; nt < 4; nt++)
#pragma unroll
            for (int kk = 0; kk < 4; kk++) {
                int p = w * 4 + nt;
                int ks = half * 4 + kk;
                Bh[nt][kk] = *(const bf16x8*)(whq + ((size_t)((p * 8 + ks) * 64 + l)) * 8);
            }

#pragma unroll
        for (int kk = 0; kk < 4; kk++) {
            int ks = half * 4 + kk;
            bf16x8 Am[4];
#pragma unroll
            for (int m = 0; m < 4; m++) {
                int rA = m * 16 + (l & 15);
                int g = ks * 4 + (l >> 4);
                Am[m] = *(const bf16x8*)(&histA[rA * 512 + ((g ^ (rA & 15)) << 4)]);
            }
#pragma unroll
            for (int m = 0; m < 4; m++)
#pragma unroll
                for (int nt = 0; nt < 4; nt++)
                    acc[m][nt] = __builtin_amdgcn_mfma_f32_16x16x32_bf16(
                        Am[m], Bh[nt][kk], acc[m][nt], 0, 0, 0);
        }
    }

    // ---- epilogue: sigmoid + qt, per-lane partial over this wave's 64 cols ----
    float pal[4][4];
#pragma unroll
    for (int m = 0; m < 4; m++)
#pragma unroll
        for (int r = 0; r < 4; r++) pal[m][r] = 0.f;

#pragma unroll
    for (int m = 0; m < 4; m++) {
#pragma unroll
        for (int nt = 0; nt < 4; nt++) {
            int col = w * 64 + nt * 16 + (l & 15);
            float qv = qtl[col], wb = wcrow[col];
#pragma unroll
            for (int r = 0; r < 4; r++) {
                float v = acc[m][nt][r] + wb;
                pal[m][r] += qv * __builtin_amdgcn_rcpf(1.0f + __expf(-v));
            }
        }
    }

    // reduce over the 16 lanes holding the 16 cols of each tile
#pragma unroll
    for (int m = 0; m < 4; m++) {
#pragma unroll
        for (int r = 0; r < 4; r++) {
            float v = pal[m][r];
            v += __shfl_xor(v, 1);
            v += __shfl_xor(v, 2);
            v += __shfl_xor(v, 4);
            v += __shfl_xor(v, 8);
            if ((l & 15) == 0)
                alphaP[w][m * 16 + (l >> 4) * 4 + r] = v;
        }
    }
    __syncthreads();
    if (tid < Hh)
        alphaF[tid] = qtb[0] + alphaP[0][tid] + alphaP[1][tid] + alphaP[2][tid] + alphaP[3][tid];
    __syncthreads();

    // history_sum = sum_h alpha[h] * hist[h], from LDS; one f32 column/thread
    {
        int d = tid;
        float a = 0.f;
#pragma unroll 2
        for (int h = 0; h < Hh; h++) {
            int g = (d >> 3) ^ (h & 15);
            unsigned short u = *(const unsigned short*)(&histA[h * 512 + (g << 4) + (d & 7) * 2]);
            unsigned int x = ((unsigned int)u) << 16;
            a += alphaF[h] * __builtin_bit_cast(float, x);
        }
        hsum_ws[(size_t)(b * 512 + s) * 256 + d] = a;
    }
}

// ---------------- Kernel 3: out[4096][128] (f32) = [cur, hsum] @ wf_w^T + wf_b ----------------
__global__ __launch_bounds__(64) void k_wf(const float* __restrict__ cur,
                                           const float* __restrict__ hsum,
                                           const float* __restrict__ wfw,
                                           const float* __restrict__ wfb,
                                           float* __restrict__ out) {
    int l = threadIdx.x;
    int m0 = (int)(blockIdx.x >> 1) * 16;
    int ntb = (int)(blockIdx.x & 1) * 4;
    int lk = (l >> 4) * 8;

    f32x4 acc[4];
#pragma unroll
    for (int nt = 0; nt < 4; nt++) acc[nt] = (f32x4){0.f, 0.f, 0.f, 0.f};

#pragma unroll
    for (int k = 0; k < 16; k++) {
        int row = m0 + (l & 15);
        bf16x8 Af;
        if (k < 8)
            Af = cvt8(cur + (size_t)row * 256 + k * 32 + lk);
        else
            Af = cvt8(hsum + (size_t)row * 256 + (k - 8) * 32 + lk);
#pragma unroll
        for (int nt = 0; nt < 4; nt++) {
            int col = (ntb + nt) * 16 + (l & 15);
            bf16x8 Bf = cvt8(wfw + (size_t)col * 512 + k * 32 + lk);
            acc[nt] = __builtin_amdgcn_mfma_f32_16x16x32_bf16(Af, Bf, acc[nt], 0, 0, 0);
        }
    }
#pragma unroll
    for (int nt = 0; nt < 4; nt++) {
        int col = (ntb + nt) * 16 + (l & 15);
        float bias = wfb[col];
        int row = m0 + (l >> 4) * 4;
#pragma unroll
        for (int r = 0; r < 4; r++)
            out[(size_t)(row + r) * 128 + col] = acc[nt][r] + bias;
    }
}

extern "C" void kernel_launch(void* const* d_in, const int* in_sizes, int n_in,
                              void* d_out, int out_size, void* d_ws, size_t ws_size,
                              hipStream_t stream) {
    const float* hist = (const float*)d_in[0];
    const float* cur  = (const float*)d_in[1];
    const float* wc_w = (const float*)d_in[2];
    const float* wc_b = (const float*)d_in[3];
    const float* wh_w = (const float*)d_in[4];
    const float* wh_b = (const float*)d_in[5];
    const float* qt_w = (const float*)d_in[6];
    const float* qt_b = (const float*)d_in[7];
    const float* wf_w = (const float*)d_in[8];
    const float* wf_b = (const float*)d_in[9];

    float* wc_ws = (float*)d_ws;                                   // 4 MB
    float* hsum  = (float*)((char*)d_ws + ((size_t)4 << 20));      // 4 MB
    short* whpk  = (short*)((char*)d_ws + ((size_t)8 << 20));      // 8 x 128 KB replicas

    k_prep<<<32, 256, 0, stream>>>(wh_w, whpk);
    k_wc<<<1024, 64, 0, stream>>>(cur, wc_w, wc_b, wc_ws);
    k_main<<<4096, 256, 0, stream>>>(hist, wc_ws, whpk, wh_b, qt_w, qt_b, hsum);
    k_wf<<<512, 64, 0, stream>>>(cur, hsum, wf_w, wf_b, (float*)d_out);
}

// Round 19
// 133.524 us; speedup vs baseline: 1.5426x; 1.0973x over previous
//
#include <hip/hip_runtime.h>
#include <hip/hip_bf16.h>

#define Hh 50

typedef __attribute__((ext_vector_type(8))) short bf16x8;
typedef __attribute__((ext_vector_type(4))) float f32x4;
typedef __attribute__((ext_vector_type(2))) float f32x2;

static __device__ __forceinline__ float bflo(unsigned int u) {
    unsigned int x = u << 16;
    return __builtin_bit_cast(float, x);
}
static __device__ __forceinline__ float bfhi(unsigned int u) {
    unsigned int x = u & 0xffff0000u;
    return __builtin_bit_cast(float, x);
}
static __device__ __forceinline__ short b16(float x) {
    return __builtin_bit_cast(short, __float2bfloat16(x));
}
// convert 8 contiguous f32 to a bf16x8 MFMA fragment
static __device__ __forceinline__ bf16x8 cvt8(const float* p) {
    f32x4 a = *(const f32x4*)p;
    f32x4 b = *(const f32x4*)(p + 4);
    bf16x8 r;
    r[0] = b16(a[0]); r[1] = b16(a[1]); r[2] = b16(a[2]); r[3] = b16(a[3]);
    r[4] = b16(b[0]); r[5] = b16(b[1]); r[6] = b16(b[2]); r[7] = b16(b[3]);
    return r;
}

// -------- Kernel 0: pack wh_w into 16x16x32 B-fragment order --------
// whpk[((p*8+ks)*64+l)*8+j] = bf16(wh_w[p*16+(l&15)][ks*32+(l>>4)*8+j])
__global__ __launch_bounds__(256) void k_prep(const float* __restrict__ w,
                                              short* __restrict__ o) {
    int t = (int)blockIdx.x * 256 + threadIdx.x;   // 0..8191
    int p  = t >> 9;
    int ks = (t >> 6) & 7;
    int l  = t & 63;
    int col = p * 16 + (l & 15);
    int k   = ks * 32 + (l >> 4) * 8;
    bf16x8 v = cvt8(w + (size_t)col * 256 + k);
    *(bf16x8*)(o + (size_t)t * 8) = v;
}

// ---------------- Kernel 1: wc_out[4096][256] (f32) = cur @ wc_w^T + wc_b ----------------
__global__ __launch_bounds__(64) void k_wc(const float* __restrict__ cur,
                                           const float* __restrict__ wcw,
                                           const float* __restrict__ wcb,
                                           float* __restrict__ out) {
    int l = threadIdx.x;
    int m0 = (int)(blockIdx.x >> 2) * 16;
    int ntb = (int)(blockIdx.x & 3) * 4;
    int lk = (l >> 4) * 8;

    bf16x8 Af[8];
#pragma unroll
    for (int k = 0; k < 8; k++)
        Af[k] = cvt8(cur + (size_t)(m0 + (l & 15)) * 256 + k * 32 + lk);

#pragma unroll
    for (int nt = 0; nt < 4; nt++) {
        int col = (ntb + nt) * 16 + (l & 15);
        f32x4 a = {0.f, 0.f, 0.f, 0.f};
#pragma unroll
        for (int k = 0; k < 8; k++) {
            bf16x8 Bf = cvt8(wcw + (size_t)col * 256 + k * 32 + lk);
            a = __builtin_amdgcn_mfma_f32_16x16x32_bf16(Af[k], Bf, a, 0, 0, 0);
        }
        float bias = wcb[col];
        int row = m0 + (l >> 4) * 4;
#pragma unroll
        for (int r = 0; r < 4; r++)
            out[(size_t)(row + r) * 256 + col] = a[r] + bias;
    }
}

// ---------------- Kernel 2: fused wh GEMM + sigmoid + qt dot + alpha*hist ----------------
// Block = (b, s0, s0+1): 2 items share one B read (B traffic halves to 256 MB).
// 112 interleaved rows (row = 2h+si; 100 real + 12 zero-pad) in swizzled LDS (57 KB).
// Wave w owns 64 cols as 2 col-groups of 32. Per cg: acc[7 mt][2 nt] (56 regs, 14
// chains); per K-half burst-load Bh[2][4] (32 regs); A streamed from LDS.
// Peak ~152 regs <= (256,3)'s 170 cap -> no spill. 2 blocks/CU (LDS-bound).
__global__ __launch_bounds__(256, 3)
void k_main(const float* __restrict__ hist,
            const float* __restrict__ wc_ws,
            const short* __restrict__ whpk,
            const float* __restrict__ whb,
            const float* __restrict__ qtw,
            const float* __restrict__ qtb,
            float* __restrict__ hsum_ws) {
    __shared__ __align__(16) char histA[112 * 512];   // swizzled bf16 [row][256]
    __shared__ float wcrow[512];                      // (wc_out + wh_b) for s0, s0+1
    __shared__ float qtl[256];
    __shared__ float alphaP[4][112];
    __shared__ float alphaF[112];

    int tid = threadIdx.x;
    int l = tid & 63;
    int w = tid >> 6;
    int b = (int)(blockIdx.x >> 8);
    int s0 = (int)(blockIdx.x & 255) * 2;

    // stage 100 hist rows (2 items interleaved: row = 2h+si) into swizzled LDS
    for (int c = tid; c < 3200; c += 256) {
        int row = c >> 5;             // 0..99
        int h = row >> 1, si = row & 1;
        int g = c & 31;
        bf16x8 v = cvt8(hist + ((size_t)(b * Hh + h) * 512 + (s0 + si)) * 256 + g * 8);
        *(bf16x8*)(&histA[row * 512 + ((g << 4) ^ ((row & 15) << 4))]) = v;
    }
    // zero pad rows 100..111
    if (tid < 384) {
        int row = 100 + (tid >> 5), g = tid & 31;
        *(f32x4*)(&histA[row * 512 + ((g << 4) ^ ((row & 15) << 4))]) = (f32x4){0.f, 0.f, 0.f, 0.f};
    }
    // combined bias: wcrow[si*256+col] = wc_out[s0+si][col] + wh_b[col]
    {
        const float* wcp = wc_ws + (size_t)(b * 512 + s0) * 256;
        wcrow[tid] = wcp[tid] + whb[tid & 255];
        wcrow[256 + tid] = wcp[256 + tid] + whb[tid & 255];
        qtl[tid] = qtw[tid];
    }
    __syncthreads();

    float pal[7][4];
#pragma unroll
    for (int mt = 0; mt < 7; mt++)
#pragma unroll
        for (int r = 0; r < 4; r++) pal[mt][r] = 0.f;

#pragma unroll 1
    for (int cg = 0; cg < 2; cg++) {
        f32x4 acc[7][2];
#pragma unroll
        for (int mt = 0; mt < 7; mt++)
#pragma unroll
            for (int nt = 0; nt < 2; nt++) acc[mt][nt] = (f32x4){0.f, 0.f, 0.f, 0.f};

#pragma unroll 1
        for (int half = 0; half < 2; half++) {
            // burst: 8 B-frags (2 nt x 4 kk), each a contiguous 1 KB wave-load
            bf16x8 Bh[2][4];
#pragma unroll
            for (int nt = 0; nt < 2; nt++)
#pragma unroll
                for (int kk = 0; kk < 4; kk++) {
                    int p = w * 4 + cg * 2 + nt;
                    int ks = half * 4 + kk;
                    Bh[nt][kk] = *(const bf16x8*)(whpk + ((size_t)((p * 8 + ks) * 64 + l)) * 8);
                }

#pragma unroll
            for (int mt = 0; mt < 7; mt++) {
                int rA = mt * 16 + (l & 15);
                bf16x8 Am[4];
#pragma unroll
                for (int kk = 0; kk < 4; kk++) {
                    int g = (half * 4 + kk) * 4 + (l >> 4);
                    Am[kk] = *(const bf16x8*)(&histA[rA * 512 + ((g << 4) ^ ((rA & 15) << 4))]);
                }
#pragma unroll
                for (int kk = 0; kk < 4; kk++)
#pragma unroll
                    for (int nt = 0; nt < 2; nt++)
                        acc[mt][nt] = __builtin_amdgcn_mfma_f32_16x16x32_bf16(
                            Am[kk], Bh[nt][kk], acc[mt][nt], 0, 0, 0);
            }
        }

        // epilogue for this cg's 32 cols: sigmoid + qt into pal
#pragma unroll
        for (int mt = 0; mt < 7; mt++)
#pragma unroll
            for (int nt = 0; nt < 2; nt++) {
                int col = w * 64 + cg * 32 + nt * 16 + (l & 15);
                float qv = qtl[col];
                float wb0 = wcrow[col], wb1 = wcrow[256 + col];
#pragma unroll
                for (int r = 0; r < 4; r++) {
                    float v = acc[mt][nt][r] + ((r & 1) ? wb1 : wb0);
                    pal[mt][r] += qv * __builtin_amdgcn_rcpf(1.0f + __expf(-v));
                }
            }
    }

    // reduce over the 16 col-lanes of each row-group
#pragma unroll
    for (int mt = 0; mt < 7; mt++) {
#pragma unroll
        for (int r = 0; r < 4; r++) {
            float v = pal[mt][r];
            v += __shfl_xor(v, 1);
            v += __shfl_xor(v, 2);
            v += __shfl_xor(v, 4);
            v += __shfl_xor(v, 8);
            if ((l & 15) == 0)
                alphaP[w][mt * 16 + (l >> 4) * 4 + r] = v;
        }
    }
    __syncthreads();
    if (tid < 112)
        alphaF[tid] = qtb[0] + alphaP[0][tid] + alphaP[1][tid] + alphaP[2][tid] + alphaP[3][tid];
    __syncthreads();

    // history_sum: thread = (si, dword-pair); rows 2h+si from LDS
    {
        int d2 = tid & 127;
        int si = tid >> 7;
        float a0 = 0.f, a1 = 0.f;
#pragma unroll 2
        for (int h = 0; h < Hh; h++) {
            int row = 2 * h + si;
            unsigned int u = *(const unsigned int*)(&histA[row * 512 + ((d2 * 4) ^ ((row & 15) << 4))]);
            float a = alphaF[row];
            a0 += a * bflo(u);
            a1 += a * bfhi(u);
        }
        f32x2 hv = {a0, a1};
        *(f32x2*)(hsum_ws + (size_t)(b * 512 + s0 + si) * 256 + d2 * 2) = hv;
    }
}

// ---------------- Kernel 3: out[4096][128] (f32) = [cur, hsum] @ wf_w^T + wf_b ----------------
__global__ __launch_bounds__(64) void k_wf(const float* __restrict__ cur,
                                           const float* __restrict__ hsum,
                                           const float* __restrict__ wfw,
                                           const float* __restrict__ wfb,
                                           float* __restrict__ out) {
    int l = threadIdx.x;
    int m0 = (int)(blockIdx.x >> 1) * 16;
    int ntb = (int)(blockIdx.x & 1) * 4;
    int lk = (l >> 4) * 8;

    f32x4 acc[4];
#pragma unroll
    for (int nt = 0; nt < 4; nt++) acc[nt] = (f32x4){0.f, 0.f, 0.f, 0.f};

#pragma unroll
    for (int k = 0; k < 16; k++) {
        int row = m0 + (l & 15);
        bf16x8 Af;
        if (k < 8)
            Af = cvt8(cur + (size_t)row * 256 + k * 32 + lk);
        else
            Af = cvt8(hsum + (size_t)row * 256 + (k - 8) * 32 + lk);
#pragma unroll
        for (int nt = 0; nt < 4; nt++) {
            int col = (ntb + nt) * 16 + (l & 15);
            bf16x8 Bf = cvt8(wfw + (size_t)col * 512 + k * 32 + lk);
            acc[nt] = __builtin_amdgcn_mfma_f32_16x16x32_bf16(Af, Bf, acc[nt], 0, 0, 0);
        }
    }
#pragma unroll
    for (int nt = 0; nt < 4; nt++) {
        int col = (ntb + nt) * 16 + (l & 15);
        float bias = wfb[col];
        int row = m0 + (l >> 4) * 4;
#pragma unroll
        for (int r = 0; r < 4; r++)
            out[(size_t)(row + r) * 128 + col] = acc[nt][r] + bias;
    }
}

extern "C" void kernel_launch(void* const* d_in, const int* in_sizes, int n_in,
                              void* d_out, int out_size, void* d_ws, size_t ws_size,
                              hipStream_t stream) {
    const float* hist = (const float*)d_in[0];
    const float* cur  = (const float*)d_in[1];
    const float* wc_w = (const float*)d_in[2];
    const float* wc_b = (const float*)d_in[3];
    const float* wh_w = (const float*)d_in[4];
    const float* wh_b = (const float*)d_in[5];
    const float* qt_w = (const float*)d_in[6];
    const float* qt_b = (const float*)d_in[7];
    const float* wf_w = (const float*)d_in[8];
    const float* wf_b = (const float*)d_in[9];

    float* wc_ws = (float*)d_ws;                                   // 4 MB
    float* hsum  = (float*)((char*)d_ws + ((size_t)4 << 20));      // 4 MB
    short* whpk  = (short*)((char*)d_ws + ((size_t)8 << 20));      // 128 KB

    k_prep<<<32, 256, 0, stream>>>(wh_w, whpk);
    k_wc<<<1024, 64, 0, stream>>>(cur, wc_w, wc_b, wc_ws);
    k_main<<<2048, 256, 0, stream>>>(hist, wc_ws, whpk, wh_b, qt_w, qt_b, hsum);
    k_wf<<<512, 64, 0, stream>>>(cur, hsum, wf_w, wf_b, (float*)d_out);
}